// Round 1
// baseline (6810.295 us; speedup 1.0000x reference)
//
#include <hip/hip_runtime.h>
#include <cstdint>

#define B_SZ 256
#define T_SZ 256
#define I_SZ 512
#define H_SZ 512
#define HALF 256

typedef __attribute__((ext_vector_type(8))) __bf16 bf16x8;
typedef __attribute__((ext_vector_type(8))) short short8;
typedef __attribute__((ext_vector_type(4))) float f32x4;
typedef __attribute__((ext_vector_type(4))) unsigned int uint4v;

__device__ __forceinline__ unsigned short f2bf(float f) {
  unsigned int u = __float_as_uint(f);
  u = (u + 0x7FFFu + ((u >> 16) & 1u)) >> 16;   // RNE
  return (unsigned short)u;
}

__device__ __forceinline__ float sigm(float x) {
  return __builtin_amdgcn_rcpf(1.f + __expf(-x));
}
__device__ __forceinline__ float tanh_(float x) {
  float ax = fabsf(x);
  float e = __expf(-2.f * ax);
  float r = (1.f - e) * __builtin_amdgcn_rcpf(1.f + e);
  return copysignf(r, x);
}

// ---------------- prepass: fp32 -> bf16 (8 elems/thread) ----------------
__global__ void cvt_f32_bf16(const float* __restrict__ src, unsigned short* __restrict__ dst) {
  long i = ((long)blockIdx.x * 256 + threadIdx.x) * 8;
  float4 a = *(const float4*)(src + i);
  float4 b = *(const float4*)(src + i + 4);
  unsigned int w0 = (unsigned)f2bf(a.x) | ((unsigned)f2bf(a.y) << 16);
  unsigned int w1 = (unsigned)f2bf(a.z) | ((unsigned)f2bf(a.w) << 16);
  unsigned int w2 = (unsigned)f2bf(b.x) | ((unsigned)f2bf(b.y) << 16);
  unsigned int w3 = (unsigned)f2bf(b.z) | ((unsigned)f2bf(b.w) << 16);
  uint4v v = {w0, w1, w2, w3};
  *(uint4v*)(dst + i) = v;
}

// ---------------- prepass: pack W_ih / W_hh into per-lane MFMA-B fragment order ----
// chunk id (per matrix): hg[4b] | w[2b] | nt[1b] | ks[4b] | lane[6b]; 8 bf16 per chunk.
// fragment element: W[w*512 + hg*32 + nt*16 + (lane&15)][ks*32 + (lane>>4)*8 + j]
__global__ void pack_w(const float* __restrict__ Wih, const float* __restrict__ Whh,
                       unsigned short* __restrict__ wp, unsigned short* __restrict__ hp) {
  int id = blockIdx.x * 256 + threadIdx.x;        // 0 .. 262143
  int cid = id & 131071;
  const float* W = (id < 131072) ? Wih : Whh;
  unsigned short* D = (id < 131072) ? wp : hp;
  int l  = cid & 63;
  int ks = (cid >> 6) & 15;
  int nt = (cid >> 10) & 1;
  int w  = (cid >> 11) & 3;
  int hg = (cid >> 13) & 15;
  int row = w * 512 + hg * 32 + nt * 16 + (l & 15);
  int k0  = ks * 32 + (l >> 4) * 8;
  const float* src = W + (long)row * 512 + k0;
  unsigned int wd[4];
#pragma unroll
  for (int j = 0; j < 4; ++j) {
    unsigned int lo = f2bf(src[2 * j]);
    unsigned int hi = f2bf(src[2 * j + 1]);
    wd[j] = lo | (hi << 16);
  }
  uint4v v = {wd[0], wd[1], wd[2], wd[3]};
  *(uint4v*)(D + (long)cid * 8) = v;
}

// ---------------- main persistent LSTM kernel ----------------
// grid 256 = 16 batch-groups (bg = blockIdx&15, keeps a group on one XCD under
// round-robin dispatch) x 16 hidden-groups (hg). Block owns batches
// [bg*16, bg*16+16) x hidden slice [hg*32, hg*32+32). Wave w = gate type w.
// Weights resident in VGPRs (2 x 128 regs). h exchanged via double-buffered
// bf16 global buffer; per-block flags, relaxed poll + acquire fence.
__global__ __launch_bounds__(256, 1) void lstm_main(
    const unsigned short* __restrict__ xb,   // [B][T][I] bf16
    const float* __restrict__ c0,
    const float* __restrict__ b_ih, const float* __restrict__ b_hh,
    const unsigned short* __restrict__ wihp, const unsigned short* __restrict__ whhp,
    unsigned short* __restrict__ hbuf,       // 2 x [B][H] bf16
    int* __restrict__ flags,                 // [16 groups][64 pad]
    float* __restrict__ out)
{
  const int tid  = threadIdx.x;
  const int lane = tid & 63;
  const int w    = tid >> 6;           // wave id == gate type (i,f,g,o)
  const int bg   = blockIdx.x & 15;
  const int hg   = blockIdx.x >> 4;
  const int s0   = hg * 32;
  const int q    = lane >> 4;
  const int c16  = lane & 15;

  __shared__ float glds[4 * 528];      // [gate][b*33 + jj], pad 33 vs bank conflicts

  // ---- load resident weight fragments (constant indices only -> stay in VGPRs)
  bf16x8 wih[2][16], whh[2][16];
#pragma unroll
  for (int nt = 0; nt < 2; ++nt) {
#pragma unroll
    for (int ks = 0; ks < 16; ++ks) {
      int idc = ((hg * 4 + w) * 2 + nt) * 16 + ks;
      long off = ((long)(idc * 64 + lane)) * 8;
      wih[nt][ks] = __builtin_bit_cast(bf16x8, *(const short8*)(wihp + off));
      whh[nt][ks] = __builtin_bit_cast(bf16x8, *(const short8*)(whhp + off));
    }
  }

  // ---- per-thread recurrent state: 2 items (b = tid>>5 and +8, jj = tid&31)
  const int jj  = tid & 31;
  const int bl0 = tid >> 5;            // 0..7
  const int bglob0 = bg * 16 + bl0;
  const int bglob1 = bglob0 + 8;
  float bias_v[4];
#pragma unroll
  for (int g = 0; g < 4; ++g)
    bias_v[g] = b_ih[g * 512 + s0 + jj] + b_hh[g * 512 + s0 + jj];
  float cst0 = c0[(long)bglob0 * H_SZ + s0 + jj];
  float cst1 = c0[(long)bglob1 * H_SZ + s0 + jj];
  float m0 = -INFINITY, m1 = -INFINITY;

  const unsigned short* xbase = xb + (long)(bg * 16 + c16) * T_SZ * I_SZ + q * 8;
  int* gflags = flags + bg * 64;

#pragma unroll 1
  for (int t = 0; t < T_SZ; ++t) {
    f32x4 acc0 = {0.f, 0.f, 0.f, 0.f};
    f32x4 acc1 = {0.f, 0.f, 0.f, 0.f};

    // ---- phase A: x projection (no dependence on h -> runs before the wait)
    const unsigned short* xt = xbase + (long)t * I_SZ;
#pragma unroll
    for (int ks = 0; ks < 16; ++ks) {
      bf16x8 a = __builtin_bit_cast(bf16x8, *(const short8*)(xt + ks * 32));
      acc0 = __builtin_amdgcn_mfma_f32_16x16x32_bf16(a, wih[0][ks], acc0, 0, 0, 0);
      acc1 = __builtin_amdgcn_mfma_f32_16x16x32_bf16(a, wih[1][ks], acc1, 0, 0, 0);
    }

    // ---- phase B: wait for all 16 producers of h_{t-1} in this batch group
    if (t > 0) {
      if (lane < 16) {
        while (__hip_atomic_load(&gflags[lane], __ATOMIC_RELAXED, __HIP_MEMORY_SCOPE_AGENT) < t)
          __builtin_amdgcn_s_sleep(1);
      }
      __threadfence();   // acquire: make producers' h stores visible
    }

    // ---- phase C: recurrent projection from h_{t-1} (buffer (t+1)&1)
    const unsigned short* hb = hbuf + ((t + 1) & 1) * (B_SZ * H_SZ)
                                    + (long)(bg * 16 + c16) * H_SZ + q * 8;
#pragma unroll
    for (int ks = 0; ks < 16; ++ks) {
      bf16x8 a = __builtin_bit_cast(bf16x8, *(const short8*)(hb + ks * 32));
      acc0 = __builtin_amdgcn_mfma_f32_16x16x32_bf16(a, whh[0][ks], acc0, 0, 0, 0);
      acc1 = __builtin_amdgcn_mfma_f32_16x16x32_bf16(a, whh[1][ks], acc1, 0, 0, 0);
    }

    // ---- phase D: gates -> LDS (D layout: row=q*4+r (batch), col=lane&15)
#pragma unroll
    for (int r = 0; r < 4; ++r) {
      glds[w * 528 + (q * 4 + r) * 33 + c16]      = acc0[r];
      glds[w * 528 + (q * 4 + r) * 33 + 16 + c16] = acc1[r];
    }
    __syncthreads();

    // ---- phase E: elementwise LSTM cell, 2 items per thread
#pragma unroll
    for (int it = 0; it < 2; ++it) {
      int b   = bl0 + it * 8;
      int bgl = bg * 16 + b;
      float gi = glds[0 * 528 + b * 33 + jj] + bias_v[0];
      float gf = glds[1 * 528 + b * 33 + jj] + bias_v[1];
      float gg = glds[2 * 528 + b * 33 + jj] + bias_v[2];
      float go = glds[3 * 528 + b * 33 + jj] + bias_v[3];
      float& cs = it ? cst1 : cst0;
      float& mm = it ? m1 : m0;
      cs = sigm(gf) * cs + sigm(gi) * tanh_(gg);
      float h = sigm(go) * tanh_(cs);
      hbuf[(t & 1) * (B_SZ * H_SZ) + (long)bgl * H_SZ + s0 + jj] = f2bf(h);
      if (hg < 8) {
        mm = fmaxf(mm, h);
        out[(long)bgl * (T_SZ * HALF) + t * HALF + s0 + jj] = mm;
      } else {
        out[(long)(256 + bgl) * (T_SZ * HALF) + t * HALF + (s0 - 256) + jj] = h;
      }
      if (t == T_SZ - 1) {
        out[33554432L + (long)bgl * H_SZ + s0 + jj] = h;
        out[33554432L + 131072L + (long)bgl * H_SZ + s0 + jj] = cs;
      }
    }
    __syncthreads();   // all h-stores/LDS-reads of this step done

    // ---- publish h_t
    if (tid == 0) {
      __threadfence();  // release: flush this block's h stores
      __hip_atomic_store(&gflags[hg], t + 1, __ATOMIC_RELEASE, __HIP_MEMORY_SCOPE_AGENT);
    }
  }
}

extern "C" void kernel_launch(void* const* d_in, const int* in_sizes, int n_in,
                              void* d_out, int out_size, void* d_ws, size_t ws_size,
                              hipStream_t stream) {
  const float* x   = (const float*)d_in[0];
  const float* h0  = (const float*)d_in[1];
  const float* c0  = (const float*)d_in[2];
  const float* Wih = (const float*)d_in[3];
  const float* Whh = (const float*)d_in[4];
  const float* bih = (const float*)d_in[5];
  const float* bhh = (const float*)d_in[6];
  float* out = (float*)d_out;

  char* ws = (char*)d_ws;
  unsigned short* xb   = (unsigned short*)(ws);              // 67,108,864 B
  unsigned short* wihp = (unsigned short*)(ws + 67108864);   //  2,097,152 B
  unsigned short* whhp = (unsigned short*)(ws + 69206016);   //  2,097,152 B
  unsigned short* hbuf = (unsigned short*)(ws + 71303168);   //    524,288 B
  int* flags           = (int*)(ws + 71827456);              //      4,096 B

  hipMemsetAsync(flags, 0, 4096, stream);
  cvt_f32_bf16<<<16384, 256, 0, stream>>>(x, xb);                 // x -> bf16
  cvt_f32_bf16<<<64, 256, 0, stream>>>(h0, hbuf + B_SZ * H_SZ);   // h0 -> buf 1
  pack_w<<<1024, 256, 0, stream>>>(Wih, Whh, wihp, whhp);
  lstm_main<<<256, 256, 0, stream>>>(xb, c0, bih, bhh, wihp, whhp, hbuf, flags, out);
}

// Round 2
// 1785.963 us; speedup vs baseline: 3.8132x; 3.8132x over previous
//
#include <hip/hip_runtime.h>
#include <cstdint>

#define B_SZ 256
#define T_SZ 256
#define I_SZ 512
#define H_SZ 512
#define HALF 256

typedef __attribute__((ext_vector_type(8))) __bf16 bf16x8;
typedef __attribute__((ext_vector_type(8))) short short8;
typedef __attribute__((ext_vector_type(4))) float f32x4;
typedef __attribute__((ext_vector_type(4))) unsigned int uint4v;

__device__ __forceinline__ unsigned short f2bf(float f) {
  unsigned int u = __float_as_uint(f);
  u = (u + 0x7FFFu + ((u >> 16) & 1u)) >> 16;   // RNE
  return (unsigned short)u;
}

__device__ __forceinline__ float sigm(float x) {
  return __builtin_amdgcn_rcpf(1.f + __expf(-x));
}
__device__ __forceinline__ float tanh_(float x) {
  float ax = fabsf(x);
  float e = __expf(-2.f * ax);
  float r = (1.f - e) * __builtin_amdgcn_rcpf(1.f + e);
  return copysignf(r, x);
}

// ---------------- prepass: fp32 -> bf16 (8 elems/thread) ----------------
__global__ void cvt_f32_bf16(const float* __restrict__ src, unsigned short* __restrict__ dst) {
  long i = ((long)blockIdx.x * 256 + threadIdx.x) * 8;
  float4 a = *(const float4*)(src + i);
  float4 b = *(const float4*)(src + i + 4);
  unsigned int w0 = (unsigned)f2bf(a.x) | ((unsigned)f2bf(a.y) << 16);
  unsigned int w1 = (unsigned)f2bf(a.z) | ((unsigned)f2bf(a.w) << 16);
  unsigned int w2 = (unsigned)f2bf(b.x) | ((unsigned)f2bf(b.y) << 16);
  unsigned int w3 = (unsigned)f2bf(b.z) | ((unsigned)f2bf(b.w) << 16);
  uint4v v = {w0, w1, w2, w3};
  *(uint4v*)(dst + i) = v;
}

// ---------------- prepass: pack W_ih / W_hh into per-lane MFMA-B fragment order ----
__global__ void pack_w(const float* __restrict__ Wih, const float* __restrict__ Whh,
                       unsigned short* __restrict__ wp, unsigned short* __restrict__ hp) {
  int id = blockIdx.x * 256 + threadIdx.x;        // 0 .. 262143
  int cid = id & 131071;
  const float* W = (id < 131072) ? Wih : Whh;
  unsigned short* D = (id < 131072) ? wp : hp;
  int l  = cid & 63;
  int ks = (cid >> 6) & 15;
  int nt = (cid >> 10) & 1;
  int w  = (cid >> 11) & 3;
  int hg = (cid >> 13) & 15;
  int row = w * 512 + hg * 32 + nt * 16 + (l & 15);
  int k0  = ks * 32 + (l >> 4) * 8;
  const float* src = W + (long)row * 512 + k0;
  unsigned int wd[4];
#pragma unroll
  for (int j = 0; j < 4; ++j) {
    unsigned int lo = f2bf(src[2 * j]);
    unsigned int hi = f2bf(src[2 * j + 1]);
    wd[j] = lo | (hi << 16);
  }
  uint4v v = {wd[0], wd[1], wd[2], wd[3]};
  *(uint4v*)(D + (long)cid * 8) = v;
}

// ---------------- main persistent LSTM kernel ----------------
// grid 256 = 16 batch-groups (bg) x 16 hidden-groups (hg). Block owns batches
// [bg*16, bg*16+16) x hidden slice [hg*32, hg*32+32). Wave w = gate type.
// Weights resident in registers. h exchanged as packed bf16x2 words through
// the coherence point (system-scope RELAXED atomics, sc0|sc1 -> Infinity
// Cache, cross-XCD coherent). NO cache-maintenance fences anywhere:
// ordering is vmcnt(0) + flag store (producer), flag poll + issue-after
// (consumer). This removes the per-step buffer_wbl2/buffer_inv that made
// round-1 take 26 us/step.
__global__ __launch_bounds__(256, 1) void lstm_main(
    const unsigned short* __restrict__ xb,   // [B][T][I] bf16
    const float* __restrict__ c0,
    const float* __restrict__ b_ih, const float* __restrict__ b_hh,
    const unsigned short* __restrict__ wihp, const unsigned short* __restrict__ whhp,
    unsigned int* __restrict__ hw,           // 2 x [B][H/2] packed bf16x2 words
    int* __restrict__ flags,                 // [16 groups][64 pad]
    float* __restrict__ out)
{
  const int tid  = threadIdx.x;
  const int lane = tid & 63;
  const int w    = tid >> 6;           // wave id == gate type (i,f,g,o)
  const int bg   = blockIdx.x & 15;
  const int hg   = blockIdx.x >> 4;
  const int s0   = hg * 32;
  const int q    = lane >> 4;
  const int c16  = lane & 15;

  __shared__ float glds[4 * 528];           // gates [gate][b*33 + jj]
  __shared__ unsigned int hpad[16 * 260];   // h_{t-1} [b][260 words] (512+8 pad)
  __shared__ unsigned short hl[512];        // this block's h slice [b][jj]

  // ---- resident weight fragments
  bf16x8 wih[2][16], whh[2][16];
#pragma unroll
  for (int nt = 0; nt < 2; ++nt) {
#pragma unroll
    for (int ks = 0; ks < 16; ++ks) {
      int idc = ((hg * 4 + w) * 2 + nt) * 16 + ks;
      long off = ((long)(idc * 64 + lane)) * 8;
      wih[nt][ks] = __builtin_bit_cast(bf16x8, *(const short8*)(wihp + off));
      whh[nt][ks] = __builtin_bit_cast(bf16x8, *(const short8*)(whhp + off));
    }
  }

  // ---- per-thread recurrent state: 2 items (b = tid>>5 and +8, jj = tid&31)
  const int jj  = tid & 31;
  const int bl0 = tid >> 5;            // 0..7
  const int bglob0 = bg * 16 + bl0;
  const int bglob1 = bglob0 + 8;
  float bias_v[4];
#pragma unroll
  for (int g = 0; g < 4; ++g)
    bias_v[g] = b_ih[g * 512 + s0 + jj] + b_hh[g * 512 + s0 + jj];
  float cst0 = c0[(long)bglob0 * H_SZ + s0 + jj];
  float cst1 = c0[(long)bglob1 * H_SZ + s0 + jj];
  float m0 = -INFINITY, m1 = -INFINITY;

  const unsigned short* xbase = xb + (long)(bg * 16 + c16) * T_SZ * I_SZ + q * 8;
  int* gflags = flags + bg * 64;

  // pack-phase constants: thread tid handles word [b=tid>>4][col=(tid&15)]
  const int pb  = tid >> 4;
  const int pcw = tid & 15;
  const long pdst = (long)(bg * 16 + pb) * 256 + s0 / 2 + pcw;

#pragma unroll 1
  for (int t = 0; t < T_SZ; ++t) {
    f32x4 acc0 = {0.f, 0.f, 0.f, 0.f};
    f32x4 acc1 = {0.f, 0.f, 0.f, 0.f};

    // ---- phase A: x projection (independent of h -> runs before the wait)
    const unsigned short* xt = xbase + (long)t * I_SZ;
#pragma unroll
    for (int ks = 0; ks < 16; ++ks) {
      bf16x8 a = __builtin_bit_cast(bf16x8, *(const short8*)(xt + ks * 32));
      acc0 = __builtin_amdgcn_mfma_f32_16x16x32_bf16(a, wih[0][ks], acc0, 0, 0, 0);
      acc1 = __builtin_amdgcn_mfma_f32_16x16x32_bf16(a, wih[1][ks], acc1, 0, 0, 0);
    }

    // ---- phase B: wait for the 16 producers of h_{t-1} (wave 0 polls)
    if (t > 0 && tid < 16) {
      while (__hip_atomic_load(&gflags[tid], __ATOMIC_RELAXED,
                               __HIP_MEMORY_SCOPE_SYSTEM) < t)
        __builtin_amdgcn_s_sleep(1);
    }
    __syncthreads();   // also a compiler barrier: h loads issue after poll

    // ---- phase B2: cooperative h_{t-1} fetch -> LDS (padded rows)
    {
      const unsigned int base = ((t + 1) & 1) * (B_SZ * H_SZ / 2) + bg * 16 * 256;
      unsigned int tmp[16];
#pragma unroll
      for (int i = 0; i < 16; ++i)
        tmp[i] = __hip_atomic_load(&hw[base + i * 256 + tid], __ATOMIC_RELAXED,
                                   __HIP_MEMORY_SCOPE_SYSTEM);
#pragma unroll
      for (int i = 0; i < 16; ++i)
        hpad[i * 260 + tid] = tmp[i];
    }
    __syncthreads();

    // ---- phase C: recurrent projection from LDS
    const unsigned int* hrow = hpad + c16 * 260;
#pragma unroll
    for (int ks = 0; ks < 16; ++ks) {
      bf16x8 a = __builtin_bit_cast(bf16x8, *(const short8*)(hrow + ks * 16 + q * 4));
      acc0 = __builtin_amdgcn_mfma_f32_16x16x32_bf16(a, whh[0][ks], acc0, 0, 0, 0);
      acc1 = __builtin_amdgcn_mfma_f32_16x16x32_bf16(a, whh[1][ks], acc1, 0, 0, 0);
    }

    // ---- phase D: gates -> LDS (D layout: row=q*4+r (batch), col=lane&15)
#pragma unroll
    for (int r = 0; r < 4; ++r) {
      glds[w * 528 + (q * 4 + r) * 33 + c16]      = acc0[r];
      glds[w * 528 + (q * 4 + r) * 33 + 16 + c16] = acc1[r];
    }
    __syncthreads();

    // ---- phase E: elementwise LSTM cell, 2 items per thread
#pragma unroll
    for (int it = 0; it < 2; ++it) {
      int b   = bl0 + it * 8;
      int bgl = bg * 16 + b;
      float gi = glds[0 * 528 + b * 33 + jj] + bias_v[0];
      float gf = glds[1 * 528 + b * 33 + jj] + bias_v[1];
      float gg = glds[2 * 528 + b * 33 + jj] + bias_v[2];
      float go = glds[3 * 528 + b * 33 + jj] + bias_v[3];
      float& cs = it ? cst1 : cst0;
      float& mm = it ? m1 : m0;
      cs = sigm(gf) * cs + sigm(gi) * tanh_(gg);
      float h = sigm(go) * tanh_(cs);
      hl[b * 32 + jj] = f2bf(h);
      if (hg < 8) {
        mm = fmaxf(mm, h);
        out[(long)bgl * (T_SZ * HALF) + t * HALF + s0 + jj] = mm;
      } else {
        out[(long)(256 + bgl) * (T_SZ * HALF) + t * HALF + (s0 - 256) + jj] = h;
      }
      if (t == T_SZ - 1) {
        out[33554432L + (long)bgl * H_SZ + s0 + jj] = h;
        out[33554432L + 131072L + (long)bgl * H_SZ + s0 + jj] = cs;
      }
    }
    __syncthreads();

    // ---- phase F: publish h_t as packed words through the coherence point
    {
      unsigned int word = ((const unsigned int*)hl)[tid];
      __hip_atomic_store(&hw[(unsigned)((t & 1) * (B_SZ * H_SZ / 2)) + pdst],
                         word, __ATOMIC_RELAXED, __HIP_MEMORY_SCOPE_SYSTEM);
      __asm__ __volatile__("s_waitcnt vmcnt(0)" ::: "memory");
    }
    __syncthreads();
    if (tid == 0) {
      __hip_atomic_store(&gflags[hg], t + 1, __ATOMIC_RELAXED,
                         __HIP_MEMORY_SCOPE_SYSTEM);
    }
  }
}

extern "C" void kernel_launch(void* const* d_in, const int* in_sizes, int n_in,
                              void* d_out, int out_size, void* d_ws, size_t ws_size,
                              hipStream_t stream) {
  const float* x   = (const float*)d_in[0];
  const float* h0  = (const float*)d_in[1];
  const float* c0  = (const float*)d_in[2];
  const float* Wih = (const float*)d_in[3];
  const float* Whh = (const float*)d_in[4];
  const float* bih = (const float*)d_in[5];
  const float* bhh = (const float*)d_in[6];
  float* out = (float*)d_out;

  char* ws = (char*)d_ws;
  unsigned short* xb   = (unsigned short*)(ws);              // 67,108,864 B
  unsigned short* wihp = (unsigned short*)(ws + 67108864);   //  2,097,152 B
  unsigned short* whhp = (unsigned short*)(ws + 69206016);   //  2,097,152 B
  unsigned int*   hw   = (unsigned int*)(ws + 71303168);     //    524,288 B
  int* flags           = (int*)(ws + 71827456);              //      4,096 B

  hipMemsetAsync(flags, 0, 4096, stream);
  cvt_f32_bf16<<<16384, 256, 0, stream>>>(x, xb);            // x -> bf16
  cvt_f32_bf16<<<64, 256, 0, stream>>>(h0, (unsigned short*)(hw + B_SZ * H_SZ / 2));
  pack_w<<<1024, 256, 0, stream>>>(Wih, Whh, wihp, whhp);
  lstm_main<<<256, 256, 0, stream>>>(xb, c0, bih, bhh, wihp, whhp, hw, flags, out);
}

// Round 3
// 1542.034 us; speedup vs baseline: 4.4164x; 1.1582x over previous
//
#include <hip/hip_runtime.h>
#include <cstdint>

#define B_SZ 256
#define T_SZ 256
#define I_SZ 512
#define H_SZ 512
#define HALF 256

typedef __attribute__((ext_vector_type(8))) __bf16 bf16x8;
typedef __attribute__((ext_vector_type(8))) short short8;
typedef __attribute__((ext_vector_type(4))) float f32x4;
typedef __attribute__((ext_vector_type(4))) unsigned int uint4v;

__device__ __forceinline__ unsigned short f2bf(float f) {
  unsigned int u = __float_as_uint(f);
  u = (u + 0x7FFFu + ((u >> 16) & 1u)) >> 16;   // RNE
  return (unsigned short)u;
}

__device__ __forceinline__ float sigm(float x) {
  return __builtin_amdgcn_rcpf(1.f + __expf(-x));
}
__device__ __forceinline__ float tanh_(float x) {
  float ax = fabsf(x);
  float e = __expf(-2.f * ax);
  float r = (1.f - e) * __builtin_amdgcn_rcpf(1.f + e);
  return copysignf(r, x);
}

// ---------------- prepass: fp32 -> bf16 (8 elems/thread) ----------------
__global__ void cvt_f32_bf16(const float* __restrict__ src, unsigned short* __restrict__ dst) {
  long i = ((long)blockIdx.x * 256 + threadIdx.x) * 8;
  float4 a = *(const float4*)(src + i);
  float4 b = *(const float4*)(src + i + 4);
  unsigned int w0 = (unsigned)f2bf(a.x) | ((unsigned)f2bf(a.y) << 16);
  unsigned int w1 = (unsigned)f2bf(a.z) | ((unsigned)f2bf(a.w) << 16);
  unsigned int w2 = (unsigned)f2bf(b.x) | ((unsigned)f2bf(b.y) << 16);
  unsigned int w3 = (unsigned)f2bf(b.z) | ((unsigned)f2bf(b.w) << 16);
  uint4v v = {w0, w1, w2, w3};
  *(uint4v*)(dst + i) = v;
}

// ---------------- prepass: h0 -> tagged u64 words (tag = 0) ----------------
__global__ void cvt_h0_tag(const float* __restrict__ h0, unsigned long long* __restrict__ dst) {
  int i = blockIdx.x * 256 + threadIdx.x;          // 0..65535 words
  unsigned int pw = (unsigned)f2bf(h0[2 * i]) | ((unsigned)f2bf(h0[2 * i + 1]) << 16);
  dst[i] = (unsigned long long)pw;                 // high 32 = tag 0
}

// ---------------- prepass: pack W_ih / W_hh into per-lane MFMA-B fragment order ----
__global__ void pack_w(const float* __restrict__ Wih, const float* __restrict__ Whh,
                       unsigned short* __restrict__ wp, unsigned short* __restrict__ hp) {
  int id = blockIdx.x * 256 + threadIdx.x;        // 0 .. 262143
  int cid = id & 131071;
  const float* W = (id < 131072) ? Wih : Whh;
  unsigned short* D = (id < 131072) ? wp : hp;
  int l  = cid & 63;
  int ks = (cid >> 6) & 15;
  int nt = (cid >> 10) & 1;
  int w  = (cid >> 11) & 3;
  int hg = (cid >> 13) & 15;
  int row = w * 512 + hg * 32 + nt * 16 + (l & 15);
  int k0  = ks * 32 + (l >> 4) * 8;
  const float* src = W + (long)row * 512 + k0;
  unsigned int wd[4];
#pragma unroll
  for (int j = 0; j < 4; ++j) {
    unsigned int lo = f2bf(src[2 * j]);
    unsigned int hi = f2bf(src[2 * j + 1]);
    wd[j] = lo | (hi << 16);
  }
  uint4v v = {wd[0], wd[1], wd[2], wd[3]};
  *(uint4v*)(D + (long)cid * 8) = v;
}

// ---- tagged-word exchange helpers (templated on memory scope) ----
template <int SCOPE>
__device__ __forceinline__ void poll_fetch(const unsigned long long* src,
                                           unsigned tag, int tid,
                                           unsigned int* hpad) {
  unsigned long long v[16];
#pragma unroll
  for (int i = 0; i < 16; ++i)
    v[i] = __hip_atomic_load(src + i * 256 + tid, __ATOMIC_RELAXED, SCOPE);
  bool redo = true;
  while (redo) {
    redo = false;
#pragma unroll
    for (int i = 0; i < 16; ++i) {
      if ((unsigned)(v[i] >> 32) != tag) {
        v[i] = __hip_atomic_load(src + i * 256 + tid, __ATOMIC_RELAXED, SCOPE);
        redo = true;
      }
    }
  }
#pragma unroll
  for (int i = 0; i < 16; ++i)
    hpad[i * 260 + tid] = (unsigned int)v[i];
}

template <int SCOPE>
__device__ __forceinline__ void st64(unsigned long long* p, unsigned long long v) {
  __hip_atomic_store(p, v, __ATOMIC_RELAXED, SCOPE);
}

// ---------------- main persistent LSTM kernel ----------------
// grid 256 = 16 batch-groups (bg) x 16 hidden-groups (hg). Block owns batches
// [bg*16,bg*16+16) x hidden [hg*32,hg*32+32). Wave w = gate type. Weights
// resident in registers. h exchanged as TAGGED u64 words ((t+1)<<32 | bf16x2),
// double-buffered by t&1: consumers poll the data words directly for tag
// equality -> no flags, no fences, no vmcnt drains. Deadlock/ABA-free by
// induction: a producer overwrites buffer p only after its poll succeeded,
// which requires every peer to have consumed buffer p's previous generation.
// Scope: one-time handshake counts blocks per XCD (HW_REG_XCC_ID); a group
// whose 16 blocks share one XCD uses AGENT scope (L2, ~200cyc), else SYSTEM.
__global__ __launch_bounds__(256, 1) void lstm_main(
    const unsigned short* __restrict__ xb,   // [B][T][I] bf16
    const float* __restrict__ c0,
    const float* __restrict__ b_ih, const float* __restrict__ b_hh,
    const unsigned short* __restrict__ wihp, const unsigned short* __restrict__ whhp,
    unsigned long long* __restrict__ hw64,   // 2 x [B][H/2] tagged words
    unsigned long long* __restrict__ cnt64,  // [16 groups][8] per-XCD counters
    float* __restrict__ out)
{
  const int tid  = threadIdx.x;
  const int lane = tid & 63;
  const int w    = tid >> 6;           // wave id == gate type (i,f,g,o)
  const int bg   = blockIdx.x & 15;
  const int hg   = blockIdx.x >> 4;
  const int s0   = hg * 32;
  const int q    = lane >> 4;
  const int c16  = lane & 15;

  __shared__ float glds[4 * 528];           // gates [gate][b*33 + jj]
  __shared__ unsigned int hpad[16 * 260];   // h_{t-1} [b][260 words]
  __shared__ int s_path;

  // ---- one-time scope handshake: are all 16 blocks of this group on one XCD?
  int xcd;
  asm volatile("s_getreg_b32 %0, hwreg(20, 0, 32)" : "=s"(xcd));
  xcd &= 15;
  if (tid == 0) {
    unsigned long long inc = 1ull << (8 * xcd);
    __hip_atomic_fetch_add(&cnt64[bg * 8], inc, __ATOMIC_RELAXED, __HIP_MEMORY_SCOPE_SYSTEM);
    unsigned long long m;
    do {
      __builtin_amdgcn_s_sleep(2);
      m = __hip_atomic_load(&cnt64[bg * 8], __ATOMIC_RELAXED, __HIP_MEMORY_SCOPE_SYSTEM);
    } while ((unsigned)((m * 0x0101010101010101ull) >> 56) < 16);
    s_path = (m == (16ull << (8 * xcd))) ? 1 : 0;
  }
  __syncthreads();
  const bool agent_path = (s_path != 0);

  // ---- resident weight fragments
  bf16x8 wih[2][16], whh[2][16];
#pragma unroll
  for (int nt = 0; nt < 2; ++nt) {
#pragma unroll
    for (int ks = 0; ks < 16; ++ks) {
      int idc = ((hg * 4 + w) * 2 + nt) * 16 + ks;
      long off = ((long)(idc * 64 + lane)) * 8;
      wih[nt][ks] = __builtin_bit_cast(bf16x8, *(const short8*)(wihp + off));
      whh[nt][ks] = __builtin_bit_cast(bf16x8, *(const short8*)(whhp + off));
    }
  }

  // ---- per-thread recurrent state: 2 items (b = tid>>5 and +8, jj = tid&31)
  const int jj  = tid & 31;
  const int bl0 = tid >> 5;            // 0..7
  const int bglob0 = bg * 16 + bl0;
  const int bglob1 = bglob0 + 8;
  float bias_v[4];
#pragma unroll
  for (int g = 0; g < 4; ++g)
    bias_v[g] = b_ih[g * 512 + s0 + jj] + b_hh[g * 512 + s0 + jj];
  float cst0 = c0[(long)bglob0 * H_SZ + s0 + jj];
  float cst1 = c0[(long)bglob1 * H_SZ + s0 + jj];
  float m0 = -INFINITY, m1 = -INFINITY;

  const unsigned short* xbase = xb + (long)(bg * 16 + c16) * T_SZ * I_SZ + q * 8;

#pragma unroll 1
  for (int t = 0; t < T_SZ; ++t) {
    f32x4 acc0 = {0.f, 0.f, 0.f, 0.f};
    f32x4 acc1 = {0.f, 0.f, 0.f, 0.f};

    // ---- phase A: x projection (independent of h -> overlaps peers' stores)
    const unsigned short* xt = xbase + (long)t * I_SZ;
#pragma unroll
    for (int ks = 0; ks < 16; ++ks) {
      bf16x8 a = __builtin_bit_cast(bf16x8, *(const short8*)(xt + ks * 32));
      acc0 = __builtin_amdgcn_mfma_f32_16x16x32_bf16(a, wih[0][ks], acc0, 0, 0, 0);
      acc1 = __builtin_amdgcn_mfma_f32_16x16x32_bf16(a, wih[1][ks], acc1, 0, 0, 0);
    }

    // ---- phase B: poll tagged h_{t-1} words (buffer (t+1)&1, tag == t)
    {
      const unsigned long long* src = hw64 + ((t + 1) & 1) * 65536 + bg * 4096;
      if (agent_path) poll_fetch<__HIP_MEMORY_SCOPE_AGENT>(src, (unsigned)t, tid, hpad);
      else            poll_fetch<__HIP_MEMORY_SCOPE_SYSTEM>(src, (unsigned)t, tid, hpad);
    }
    __syncthreads();

    // ---- phase C: recurrent projection from LDS
    const unsigned int* hrow = hpad + c16 * 260;
#pragma unroll
    for (int ks = 0; ks < 16; ++ks) {
      bf16x8 a = __builtin_bit_cast(bf16x8, *(const short8*)(hrow + ks * 16 + q * 4));
      acc0 = __builtin_amdgcn_mfma_f32_16x16x32_bf16(a, whh[0][ks], acc0, 0, 0, 0);
      acc1 = __builtin_amdgcn_mfma_f32_16x16x32_bf16(a, whh[1][ks], acc1, 0, 0, 0);
    }

    // ---- phase D: gates -> LDS (D layout: row=q*4+r (batch), col=lane&15)
#pragma unroll
    for (int r = 0; r < 4; ++r) {
      glds[w * 528 + (q * 4 + r) * 33 + c16]      = acc0[r];
      glds[w * 528 + (q * 4 + r) * 33 + 16 + c16] = acc1[r];
    }
    __syncthreads();

    // ---- phase E: cell math, then IMMEDIATELY publish h (shfl-paired words)
    float hv0, hv1;
#pragma unroll
    for (int it = 0; it < 2; ++it) {
      int b = bl0 + it * 8;
      float gi = glds[0 * 528 + b * 33 + jj] + bias_v[0];
      float gf = glds[1 * 528 + b * 33 + jj] + bias_v[1];
      float gg = glds[2 * 528 + b * 33 + jj] + bias_v[2];
      float go = glds[3 * 528 + b * 33 + jj] + bias_v[3];
      float& cs = it ? cst1 : cst0;
      cs = sigm(gf) * cs + sigm(gi) * tanh_(gg);
      float h = sigm(go) * tanh_(cs);
      if (it) hv1 = h; else hv0 = h;
    }
    {
      float po0 = __shfl_xor(hv0, 1);
      float po1 = __shfl_xor(hv1, 1);
      if (!(jj & 1)) {
        unsigned long long tagw = (unsigned long long)(t + 1) << 32;
        unsigned long long w0 = tagw | ((unsigned)f2bf(hv0) | ((unsigned)f2bf(po0) << 16));
        unsigned long long w1 = tagw | ((unsigned)f2bf(hv1) | ((unsigned)f2bf(po1) << 16));
        unsigned long long* d0 = hw64 + (t & 1) * 65536 + bg * 4096
                               + bl0 * 256 + (s0 >> 1) + (jj >> 1);
        if (agent_path) {
          st64<__HIP_MEMORY_SCOPE_AGENT>(d0, w0);
          st64<__HIP_MEMORY_SCOPE_AGENT>(d0 + 8 * 256, w1);
        } else {
          st64<__HIP_MEMORY_SCOPE_SYSTEM>(d0, w0);
          st64<__HIP_MEMORY_SCOPE_SYSTEM>(d0 + 8 * 256, w1);
        }
      }
    }

    // ---- phase F: outputs (off the critical path, after h is in flight)
#pragma unroll
    for (int it = 0; it < 2; ++it) {
      int b   = bl0 + it * 8;
      int bgl = bg * 16 + b;
      float h = it ? hv1 : hv0;
      float& mm = it ? m1 : m0;
      if (hg < 8) {
        mm = fmaxf(mm, h);
        out[(long)bgl * (T_SZ * HALF) + t * HALF + s0 + jj] = mm;
      } else {
        out[(long)(256 + bgl) * (T_SZ * HALF) + t * HALF + (s0 - 256) + jj] = h;
      }
      if (t == T_SZ - 1) {
        float cs = it ? cst1 : cst0;
        out[33554432L + (long)bgl * H_SZ + s0 + jj] = h;
        out[33554432L + 131072L + (long)bgl * H_SZ + s0 + jj] = cs;
      }
    }
  }
}

extern "C" void kernel_launch(void* const* d_in, const int* in_sizes, int n_in,
                              void* d_out, int out_size, void* d_ws, size_t ws_size,
                              hipStream_t stream) {
  const float* x   = (const float*)d_in[0];
  const float* h0  = (const float*)d_in[1];
  const float* c0  = (const float*)d_in[2];
  const float* Wih = (const float*)d_in[3];
  const float* Whh = (const float*)d_in[4];
  const float* bih = (const float*)d_in[5];
  const float* bhh = (const float*)d_in[6];
  float* out = (float*)d_out;

  char* ws = (char*)d_ws;
  unsigned short* xb     = (unsigned short*)(ws);              // 67,108,864 B
  unsigned short* wihp   = (unsigned short*)(ws + 67108864);   //  2,097,152 B
  unsigned short* whhp   = (unsigned short*)(ws + 69206016);   //  2,097,152 B
  unsigned long long* hw = (unsigned long long*)(ws + 71303168); // 1,048,576 B
  unsigned long long* cn = (unsigned long long*)(ws + 72351744); //     4,096 B

  hipMemsetAsync(cn, 0, 4096, stream);
  cvt_f32_bf16<<<16384, 256, 0, stream>>>(x, xb);              // x -> bf16
  cvt_h0_tag<<<256, 256, 0, stream>>>(h0, hw + 65536);         // h0 -> buf 1, tag 0
  pack_w<<<1024, 256, 0, stream>>>(Wih, Whh, wihp, whhp);
  lstm_main<<<256, 256, 0, stream>>>(xb, c0, bih, bhh, wihp, whhp, hw, cn, out);
}